// Round 1
// baseline (487.544 us; speedup 1.0000x reference)
//
#include <hip/hip_runtime.h>

#define NWIDTH 299592
#define NOUT   51360

// ---------- Lyndon machinery (rebuilt every launch; deterministic) ----------

__device__ __forceinline__ bool is_lyndon(unsigned p, int n) {
  const unsigned nb = 3u * (unsigned)n;
  const unsigned mask = (1u << nb) - 1u;
  for (int k = 1; k < n; ++k) {
    unsigned rot = ((p << (3 * k)) & mask) | (p >> (nb - 3 * k));
    if (p >= rot) return false;   // must be strictly smaller than every rotation
  }
  return true;
}

__device__ __forceinline__ int lbound(const int* __restrict__ a, int lo, int hi, int v) {
  while (lo < hi) { int m = (lo + hi) >> 1; if (a[m] < v) lo = m + 1; else hi = m; }
  return lo;
}

// Levels 1..5 (8,64,512,4096,32768 positions): one block, sequential per level.
__global__ __launch_bounds__(1024) void lyndon_small(int* __restrict__ idx_table) {
  __shared__ int cn[1024];
  const int tid = threadIdx.x;
  const int sizes[5] = {8, 64, 512, 4096, 32768};
  const int offs[5]  = {0, 8, 72, 584, 4680};     // sig flat offsets
  const int bases[5] = {0, 8, 36, 204, 1212};     // out slot bases
#pragma unroll
  for (int li = 0; li < 5; ++li) {
    const int n = li + 1, sz = sizes[li];
    const int per = (sz + 1023) >> 10;
    const int start = tid * per;
    int c = 0;
    for (int j = 0; j < per; ++j) {
      int p = start + j;
      if (p < sz && is_lyndon((unsigned)p, n)) ++c;
    }
    cn[tid] = c;
    __syncthreads();
    for (int d = 1; d < 1024; d <<= 1) {        // Hillis-Steele inclusive scan
      int t = (tid >= d) ? cn[tid - d] : 0;
      __syncthreads();
      cn[tid] += t;
      __syncthreads();
    }
    int excl = cn[tid] - c;
    int w = 0;
    for (int j = 0; j < per; ++j) {
      int p = start + j;
      if (p < sz && is_lyndon((unsigned)p, n)) {
        idx_table[bases[li] + excl + w] = offs[li] + p;
        ++w;
      }
    }
    __syncthreads();
  }
}

// Level 6: 262144 positions = 256 blocks x 1024 threads, two-pass scan.
__global__ __launch_bounds__(1024) void lyndon6_count(int* __restrict__ blkcnt) {
  const int tid = threadIdx.x;
  const unsigned p = blockIdx.x * 1024u + (unsigned)tid;
  bool f = is_lyndon(p, 6);
  unsigned long long m = __ballot(f);
  __shared__ int wsum[16];
  const int lane = tid & 63, wv = tid >> 6;
  if (lane == 0) wsum[wv] = __popcll(m);
  __syncthreads();
  if (tid == 0) {
    int s = 0;
    for (int i = 0; i < 16; ++i) s += wsum[i];
    blkcnt[blockIdx.x] = s;
  }
}

__global__ __launch_bounds__(256) void scan256(const int* __restrict__ blkcnt,
                                               int* __restrict__ blkoff) {
  __shared__ int t_[256];
  const int tid = threadIdx.x;
  int c = blkcnt[tid];
  t_[tid] = c;
  __syncthreads();
  for (int d = 1; d < 256; d <<= 1) {
    int t = (tid >= d) ? t_[tid - d] : 0;
    __syncthreads();
    t_[tid] += t;
    __syncthreads();
  }
  blkoff[tid] = t_[tid] - c;   // exclusive
}

__global__ __launch_bounds__(1024) void lyndon6_write(const int* __restrict__ blkoff,
                                                      int* __restrict__ idx_table) {
  const int tid = threadIdx.x;
  const unsigned p = blockIdx.x * 1024u + (unsigned)tid;
  bool f = is_lyndon(p, 6);
  unsigned long long m = __ballot(f);
  __shared__ int wsum[16];
  const int lane = tid & 63, wv = tid >> 6;
  if (lane == 0) wsum[wv] = __popcll(m);
  __syncthreads();
  if (tid == 0) {
    int s = 0;
    for (int i = 0; i < 16; ++i) { int t = wsum[i]; wsum[i] = s; s += t; }
  }
  __syncthreads();
  if (f) {
    int rank = blkoff[blockIdx.x] + wsum[wv] + __popcll(m & ((1ull << lane) - 1ull));
    idx_table[7764 + rank] = 37448 + (int)p;
  }
}

// ---------- main: per-(batch, first-letter) log-signature slice ----------
// sig level offsets: S1@0(8) S2@8(64) S3@72(512) S4@584(4096) S5@4680(32768) S6@37448(262144)
// LDS (32768 floats = 128 KiB), phase-overlapped:
//   iter phase : Plo[584] @0 (P2s@0,P3s@8,P4s@72) | s2c[64]@584 | s3c[528]@648 | s4c[4224]@1176
//   gather A   : L2@0(8) L3@8(64) L4@72(512) L5@584(4096)
//   gather B   : transposed L6: sm[(pl&31)*1024 + (pl>>5)]

__device__ __forceinline__ int pad32(int i) { return i + (i >> 5); }

__global__ __launch_bounds__(1024) void logsig_main(const float* __restrict__ sig,
                                                    const int* __restrict__ idx_table,
                                                    float* __restrict__ out) {
  extern __shared__ float sm[];
  const int tid = threadIdx.x;
  const int bid = blockIdx.x;
  // XCD swizzle: all 8 j1-blocks of a batch land on one XCD (512 = 8 XCD x 64)
  const int xcd = bid & 7;
  const int g   = bid >> 3;
  const int b   = xcd * 8 + (g >> 3);
  const int j1  = g & 7;

  const float* __restrict__ S  = sig + (size_t)b * NWIDTH;
  const float* __restrict__ S2 = S + 8;
  const float* __restrict__ S3 = S + 72;
  const float* __restrict__ S4 = S + 584;
  const float* __restrict__ S5 = S + 4680;
  const float* __restrict__ S6 = S + 37448;

  float* Plo = sm;            // 584 floats
  float* s2c = sm + 584;      // 64
  float* s3c = sm + 648;      // 528 (padded 512)
  float* s4c = sm + 1176;     // 4224 (padded 4096)

  // ---- init (n = 1): P = S slices, L = S slices ----
  float s1v[8];
#pragma unroll
  for (int i = 0; i < 8; ++i) s1v[i] = S[i];
  float p1 = s1v[j1];
  const float s1j = p1;

  float l2 = 0.f, l3 = 0.f, l4 = 0.f;
  if (tid < 8)   { float v = S2[j1 * 8 + tid];   Plo[tid]      = v; l2 = v; }
  if (tid < 64)  { float v = S3[j1 * 64 + tid];  Plo[8 + tid]  = v; l3 = v; }
  if (tid < 512) { float v = S4[j1 * 512 + tid]; Plo[72 + tid] = v; l4 = v; }
  if (tid < 64)  s2c[tid] = S2[tid];
  if (tid < 512) s3c[pad32(tid)] = S3[tid];
  {
    float4 v = *(const float4*)(S4 + tid * 4);
    int i0 = tid * 4;
    s4c[pad32(i0)]     = v.x;
    s4c[pad32(i0 + 1)] = v.y;
    s4c[pad32(i0 + 2)] = v.z;
    s4c[pad32(i0 + 3)] = v.w;
  }
  float p5[4], l5[4];
  {
    float4 v = *(const float4*)(S5 + j1 * 4096 + tid * 4);
    p5[0] = v.x; p5[1] = v.y; p5[2] = v.z; p5[3] = v.w;
    l5[0] = v.x; l5[1] = v.y; l5[2] = v.z; l5[3] = v.w;
  }
  float l6[32];
  {
    const float4* s6v = (const float4*)(S6 + (size_t)j1 * 32768 + tid * 32);
#pragma unroll
    for (int v = 0; v < 8; ++v) {
      float4 x = s6v[v];
      l6[4 * v] = x.x; l6[4 * v + 1] = x.y; l6[4 * v + 2] = x.z; l6[4 * v + 3] = x.w;
    }
  }
  __syncthreads();

  // ---- Horner iterations: P <- P (x) S, L += coef_n * P ----
  const float coefs[7] = {0.f, 0.f, -0.5f, 1.f / 3.f, -0.25f, 0.2f, -1.f / 6.f};
#pragma unroll
  for (int n = 2; n <= 6; ++n) {
    const float coef = coefs[n];
    // level 6 (register slice, 32/thread); term i active iff i >= n-1
    float a6[32];
#pragma unroll
    for (int e = 0; e < 32; ++e) {
      const int r = (tid << 5) + e;
      float acc = p5[e >> 3] * s1v[e & 7];                       // i=5, always
      if (n <= 5) acc += Plo[72 + (r >> 6)] * s2c[r & 63];       // i=4
      if (n <= 4) acc += Plo[8 + (r >> 9)] * s3c[pad32(r & 511)];// i=3
      if (n <= 3) acc += Plo[(r >> 12)] * s4c[pad32(r & 4095)];  // i=2
      if (n == 2) acc += p1 * S5[r];                             // i=1
      a6[e] = acc;
    }
    // level 5 (register slice, 4/thread)
    float a5[4];
#pragma unroll
    for (int e = 0; e < 4; ++e) {
      const int q = (tid << 2) + e;
      float acc = 0.f;
      if (n <= 5) acc += Plo[72 + (q >> 3)] * s1v[q & 7];        // i=4
      if (n <= 4) acc += Plo[8 + (q >> 6)] * s2c[q & 63];        // i=3
      if (n <= 3) acc += Plo[(q >> 9)] * s3c[pad32(q & 511)];    // i=2
      if (n == 2) acc += p1 * s4c[pad32(q)];                     // i=1
      a5[e] = acc;
    }
    // levels 4,3,2 (LDS slices, owner threads)
    float t4 = 0.f, t3 = 0.f, t2 = 0.f;
    if (tid < 512) {
      if (n <= 4) t4 += Plo[8 + (tid >> 3)] * s1v[tid & 7];      // i=3
      if (n <= 3) t4 += Plo[(tid >> 6)] * s2c[tid & 63];         // i=2
      if (n == 2) t4 += p1 * s3c[pad32(tid)];                    // i=1
    }
    if (tid < 64) {
      if (n <= 3) t3 += Plo[(tid >> 3)] * s1v[tid & 7];          // i=2
      if (n == 2) t3 += p1 * s2c[tid];                           // i=1
    }
    if (tid < 8) {
      if (n == 2) t2 = p1 * s1v[tid];                            // i=1
    }
    __syncthreads();  // all reads of P_old (Plo) complete
    if (tid < 512) Plo[72 + tid] = t4;
    if (tid < 64)  Plo[8 + tid]  = t3;
    if (tid < 8)   Plo[tid]      = t2;
    p1 = 0.f;
#pragma unroll
    for (int e = 0; e < 32; ++e) l6[e] += coef * a6[e];
#pragma unroll
    for (int e = 0; e < 4; ++e) { p5[e] = a5[e]; l5[e] += coef * a5[e]; }
    l4 += coef * t4; l3 += coef * t3; l2 += coef * t2;
    __syncthreads();  // P_new visible before next iteration
  }

  // ---- gather phase ----
  float* outb = out + (size_t)b * NOUT;
  __syncthreads();
  // dump L2..L5 (overwrites dead iteration state)
  if (tid < 8)   sm[tid]      = l2;
  if (tid < 64)  sm[8 + tid]  = l3;
  if (tid < 512) sm[72 + tid] = l4;
  {
    int q4 = tid * 4;
    sm[584 + q4] = l5[0]; sm[584 + q4 + 1] = l5[1];
    sm[584 + q4 + 2] = l5[2]; sm[584 + q4 + 3] = l5[3];
  }
  if (tid == 0) outb[j1] = s1j;   // level-1 Lyndon word j1
  __syncthreads();

  const int goff[7]   = {0, 0, 8, 72, 584, 4680, 37448};
  const int gbase[7]  = {0, 0, 8, 36, 204, 1212, 7764};
  const int gcnt[7]   = {0, 8, 28, 168, 1008, 6552, 43596};
  const int gsub[7]   = {0, 1, 8, 64, 512, 4096, 32768};
  const int ldsoff[6] = {0, 0, 0, 8, 72, 584};
#pragma unroll
  for (int k = 2; k <= 5; ++k) {
    const int lo = gbase[k], hi = gbase[k] + gcnt[k];
    const int v0 = goff[k] + j1 * gsub[k];
    const int v1 = v0 + gsub[k];
    const int a0 = lbound(idx_table, lo, hi, v0);
    const int a1 = lbound(idx_table, lo, hi, v1);
    for (int o = a0 + tid; o < a1; o += 1024) {
      int pl = idx_table[o] - v0;
      outb[o] = sm[ldsoff[k] + pl];
    }
  }
  __syncthreads();
  // dump L6 transposed (conflict-free writes), then gather level 6
  {
    int r0 = tid;  // sm[e*1024 + tid]
#pragma unroll
    for (int e = 0; e < 32; ++e) sm[e * 1024 + r0] = l6[e];
  }
  __syncthreads();
  {
    const int lo = gbase[6], hi = gbase[6] + gcnt[6];
    const int v0 = goff[6] + j1 * gsub[6];
    const int v1 = v0 + gsub[6];
    const int a0 = lbound(idx_table, lo, hi, v0);
    const int a1 = lbound(idx_table, lo, hi, v1);
    for (int o = a0 + tid; o < a1; o += 1024) {
      int pl = idx_table[o] - v0;
      outb[o] = sm[(pl & 31) * 1024 + (pl >> 5)];
    }
  }
}

// ---------- launch ----------

extern "C" void kernel_launch(void* const* d_in, const int* in_sizes, int n_in,
                              void* d_out, int out_size, void* d_ws, size_t ws_size,
                              hipStream_t stream) {
  const float* sig = (const float*)d_in[0];
  float* out = (float*)d_out;
  int* idx_table = (int*)d_ws;           // 51360 ints
  int* blkcnt = idx_table + NOUT;        // 256
  int* blkoff = blkcnt + 256;            // 256

  // allow 128 KiB dynamic LDS (ignore error if unsupported/no-op on this ROCm)
  (void)hipFuncSetAttribute((const void*)logsig_main,
                            hipFuncAttributeMaxDynamicSharedMemorySize, 131072);

  lyndon_small<<<1, 1024, 0, stream>>>(idx_table);
  lyndon6_count<<<256, 1024, 0, stream>>>(blkcnt);
  scan256<<<1, 256, 0, stream>>>(blkcnt, blkoff);
  lyndon6_write<<<256, 1024, 0, stream>>>(blkoff, idx_table);
  logsig_main<<<512, 1024, 131072, stream>>>(sig, idx_table, out);
}